// Round 8
// baseline (388.011 us; speedup 1.0000x reference)
//
#include <hip/hip_runtime.h>
#include <math.h>

namespace {

constexpr int Cc  = 512;
constexpr int HW  = 196;
constexpr int HWP = 224;
constexpr int OC  = 2048;
constexpr float TEMP   = 0.35355339059327373f;  // 1/sqrt(KEY_DIM)
constexpr float INV196 = 1.0f / 196.0f;

typedef __attribute__((ext_vector_type(8))) _Float16 half8;
typedef __attribute__((ext_vector_type(4))) float f32x4;

__device__ __forceinline__ void gload_lds16(const void* g, void* l) {
  __builtin_amdgcn_global_load_lds(
      (const __attribute__((address_space(1))) void*)g,
      (__attribute__((address_space(3))) void*)l, 16, 0, 0);
}

#define MFMAH(a, b, c) __builtin_amdgcn_mfma_f32_16x16x32_f16((a), (b), (c), 0, 0, 0)

// ================= K1: wv_prep (512 blocks) || pool (4096 blocks, XCD-affine) =================
__global__ __launch_bounds__(256) void fat_prep(
    const float* __restrict__ x, const float* __restrict__ Wv,
    _Float16* __restrict__ WvA, float* __restrict__ WvT,
    _Float16* __restrict__ xpH, _Float16* __restrict__ xpL,
    float* __restrict__ xm) {
  __shared__ char sm1[8448];
  int bid = blockIdx.x;
  int t = threadIdx.x;
  if (bid < 512) {
    // ---- wv_prep: WvA fragments + WvT transpose ----
    float* tile = (float*)sm1;          // [64][33]
    int kk = bid >> 5;
    int rq = bid & 31;
    int w = t >> 6, lane = t & 63;
    int r = rq * 4 + w;
    int oc = r * 16 + (lane & 15);
    int c0 = kk * 32 + (lane >> 4) * 8;
    const float* src = Wv + (size_t)oc * 512 + c0;
    float4 v0 = *(const float4*)src;
    float4 v1 = *(const float4*)(src + 4);
    float vals[8] = {v0.x, v0.y, v0.z, v0.w, v1.x, v1.y, v1.z, v1.w};
    half8 hi, lo;
    #pragma unroll
    for (int e = 0; e < 8; ++e) {
      _Float16 h = (_Float16)vals[e];
      hi[e] = h;
      lo[e] = (_Float16)(vals[e] - (float)h);
    }
    *(half8*)(WvA + ((size_t)(kk * 2 + 0) * 128 + r) * 512 + lane * 8) = hi;
    *(half8*)(WvA + ((size_t)(kk * 2 + 1) * 128 + r) * 512 + lane * 8) = lo;
    int ocl = w * 16 + (lane & 15);
    int cl = (lane >> 4) * 8;
    #pragma unroll
    for (int e = 0; e < 8; ++e) tile[ocl * 33 + cl + e] = vals[e];
    __syncthreads();
    int ocb = rq * 64;
    #pragma unroll
    for (int k2 = 0; k2 < 8; ++k2) {
      int idx = k2 * 256 + t;
      int c_l = idx >> 6, oc_l = idx & 63;
      WvT[(size_t)(kk * 32 + c_l) * 2048 + ocb + oc_l] = tile[oc_l * 33 + c_l];
    }
  } else {
    // ---- pool: avgpool3x3 + spatial mean -> f16 hi/lo xp [nd][hw][c] ----
    float* tl = (float*)sm1;            // [8][264]
    int pb = bid - 512;
    int nd = (((pb >> 9) & 7) << 3) | (pb & 7);   // XCD-affine: same-nd cg blocks share XCD
    int cg = (pb >> 3) & 63;
    int n = nd >> 5, d = nd & 31;
    int c0 = cg * 8;
    int cl = t >> 5, s = t & 31;
    const float* xr = x + (((size_t)(n * 512 + c0 + cl)) * 32 + d) * 256;
    float4 va = *(const float4*)(xr + s * 8);
    float4 vb = *(const float4*)(xr + s * 8 + 4);
    *(float4*)&tl[cl * 264 + s * 8] = va;
    *(float4*)&tl[cl * 264 + s * 8 + 4] = vb;
    float rs = va.x + va.y + va.z + va.w + vb.x + vb.y + vb.z + vb.w;
    #pragma unroll
    for (int off = 16; off; off >>= 1) rs += __shfl_xor(rs, off, 32);
    if (s == 0) xm[nd * 512 + c0 + cl] = rs * (1.0f / 256.0f);
    __syncthreads();
    if (t < HWP) {
      int hw = t;
      half8 hi, lo;
      if (hw < HW) {
        int y = hw / 14, xx = hw - y * 14;
        #pragma unroll
        for (int c = 0; c < 8; ++c) {
          const float* q = &tl[c * 264 + y * 16 + xx];
          float val = (q[0] + q[1] + q[2] + q[16] + q[17] + q[18] +
                       q[32] + q[33] + q[34]) * (1.0f / 9.0f);
          _Float16 h = (_Float16)val;
          hi[c] = h;
          lo[c] = (_Float16)(val - (float)h);
        }
      } else {
        #pragma unroll
        for (int c = 0; c < 8; ++c) { hi[c] = (_Float16)0.f; lo[c] = (_Float16)0.f; }
      }
      size_t off = ((size_t)nd * HWP + hw) * 512 + c0;
      *(half8*)(xpH + off) = hi;
      *(half8*)(xpL + off) = lo;
    }
  }
}

// ================= K2: attn (blocks 0..255, scheduled first) || moments (256..1279) =================
__global__ __launch_bounds__(256, 4) void fat_main(
    const _Float16* __restrict__ WvA, const _Float16* __restrict__ xpH,
    const _Float16* __restrict__ xpL,
    const float* __restrict__ Wq, const float* __restrict__ Wk,
    const float* __restrict__ xm,
    float* __restrict__ attn_out, float* __restrict__ sb,
    float* __restrict__ S1, float* __restrict__ S2) {
  __shared__ char smem[26624];
  int bid = blockIdx.x;
  int t = threadIdx.x;
  int w = t >> 6, lane = t & 63;

  if (bid < 256) {
    // ---------------- attention path: q -> qw -> dots -> softmax -> s ----------------
    float* sred = (float*)smem;           // [4][512]
    float* xs   = (float*)(smem + 8192);  // [512]
    float* qw   = (float*)(smem + 10240); // [512]
    float* al   = (float*)(smem + 12288); // [196]
    float* qs   = (float*)(smem + 13072); // [8]
    float* redm = (float*)(smem + 13104); // [4]
    float* reds = (float*)(smem + 13120); // [4]
    int nd = ((bid >> 5) << 3) | (bid & 7);
    int o = (bid >> 3) & 3;
    int n = nd >> 5, d = nd & 31;
    xs[t] = xm[nd * 512 + t];
    xs[t + 256] = xm[nd * 512 + t + 256];
    __syncthreads();
    {
      int kd = t >> 5, j = t & 31;
      const float* wr = Wq + (size_t)(o * 8 + kd) * 512 + j * 16;
      const float* xr = xs + j * 16;
      float p = 0.f;
      #pragma unroll
      for (int i = 0; i < 16; ++i) p = fmaf(wr[i], xr[i], p);
      #pragma unroll
      for (int off = 16; off; off >>= 1) p += __shfl_xor(p, off, 32);
      if (j == 0) qs[kd] = p;
    }
    __syncthreads();
    #pragma unroll
    for (int i = 0; i < 2; ++i) {
      int c = t + i * 256;
      float a = 0.f;
      #pragma unroll
      for (int kd = 0; kd < 8; ++kd)
        a = fmaf(qs[kd], Wk[(size_t)(o * 8 + kd) * 512 + c], a);
      qw[c] = a;
    }
    __syncthreads();
    float dval = -3.0e38f;
    if (t < HW) {
      const half8* rh = (const half8*)(xpH + ((size_t)nd * HWP + t) * 512);
      const half8* rl = (const half8*)(xpL + ((size_t)nd * HWP + t) * 512);
      float acc = 0.f;
      for (int cb = 0; cb < 64; ++cb) {
        half8 h = rh[cb], l = rl[cb];
        #pragma unroll
        for (int e = 0; e < 8; ++e)
          acc = fmaf(qw[cb * 8 + e], (float)h[e] + (float)l[e], acc);
      }
      dval = acc * TEMP;
    }
    float m = dval;
    #pragma unroll
    for (int off = 32; off; off >>= 1) m = fmaxf(m, __shfl_xor(m, off, 64));
    if (lane == 0) redm[w] = m;
    __syncthreads();
    float bm = fmaxf(fmaxf(redm[0], redm[1]), fmaxf(redm[2], redm[3]));
    float e = (t < HW) ? expf(dval - bm) : 0.f;
    float sum = e;
    #pragma unroll
    for (int off = 32; off; off >>= 1) sum += __shfl_xor(sum, off, 64);
    if (lane == 0) reds[w] = sum;
    __syncthreads();
    float bs = reds[0] + reds[1] + reds[2] + reds[3];
    if (t < HW) {
      float a = e / bs;
      attn_out[(((size_t)n * 4 + o) * 32 + d) * HW + t] = a;
      al[t] = a;
    }
    __syncthreads();
    {
      float sa[8] = {0.f, 0.f, 0.f, 0.f, 0.f, 0.f, 0.f, 0.f};
      const _Float16* ph = xpH + (size_t)nd * HWP * 512 + lane * 8;
      const _Float16* pl = xpL + (size_t)nd * HWP * 512 + lane * 8;
      for (int hw = w; hw < HW; hw += 4) {
        half8 h = *(const half8*)(ph + (size_t)hw * 512);
        half8 l = *(const half8*)(pl + (size_t)hw * 512);
        float att = al[hw];
        #pragma unroll
        for (int e2 = 0; e2 < 8; ++e2)
          sa[e2] = fmaf(att, (float)h[e2] + (float)l[e2], sa[e2]);
      }
      float4 v0 = {sa[0], sa[1], sa[2], sa[3]};
      float4 v1 = {sa[4], sa[5], sa[6], sa[7]};
      *(float4*)&sred[w * 512 + lane * 8] = v0;
      *(float4*)&sred[w * 512 + lane * 8 + 4] = v1;
    }
    __syncthreads();
    #pragma unroll
    for (int i = 0; i < 2; ++i) {
      int c = t + i * 256;
      sb[((size_t)nd * 4 + o) * 512 + c] =
          sred[c] + sred[512 + c] + sred[1024 + c] + sred[1536 + c];
    }
    return;
  }

  // ---------------- moments path (identical to r7 moments_mfma) ----------------
  int b2 = bid - 256;
  int ob = (b2 >> 3) & 15;
  int nd = ((b2 >> 7) << 3) | (b2 & 7);
  int wq = w >> 1, wh = w & 1;
  int rbase = ob * 8 + wq * 4;
  int jbase = wh * 7;
  int nj = 7 - wh;
  char* ldsb = smem;
  const _Float16* xph = xpH + (size_t)nd * HWP * 512;

  f32x4 acc[4][7];
  #pragma unroll
  for (int f = 0; f < 4; ++f)
    #pragma unroll
    for (int j = 0; j < 7; ++j) acc[f][j] = (f32x4){0.f, 0.f, 0.f, 0.f};

  auto stage = [&](char* buf, int kk) {
    #pragma unroll
    for (int i = 0; i < 4; ++i) {
      if (i < 3 || t < 64) {
        int G = i * 256 + t;
        int j = G >> 6;
        int g = G & 63;              // == lane
        int hwl = g & 15, bb = g >> 4;
        const _Float16* src = xph + (size_t)(j * 16 + hwl) * 512 + kk * 32 + bb * 8;
        gload_lds16((const void*)src, (void*)(buf + G * 16));
      }
    }
  };

  stage(ldsb, 0);
  half8 ah[4], al_[4], nah[4], nal[4];
  #pragma unroll
  for (int f = 0; f < 4; ++f) {
    ah[f]  = *(const half8*)(WvA + ((size_t)0 * 128 + rbase + f) * 512 + lane * 8);
    al_[f] = *(const half8*)(WvA + ((size_t)1 * 128 + rbase + f) * 512 + lane * 8);
  }
  __syncthreads();

  int cur = 0;
  for (int kk = 0; kk < 16; ++kk) {
    if (kk < 15) {
      #pragma unroll
      for (int f = 0; f < 4; ++f) {
        nah[f] = *(const half8*)(WvA + ((size_t)((kk + 1) * 2 + 0) * 128 + rbase + f) * 512 + lane * 8);
        nal[f] = *(const half8*)(WvA + ((size_t)((kk + 1) * 2 + 1) * 128 + rbase + f) * 512 + lane * 8);
      }
      stage(ldsb + (cur ^ 1) * 13312, kk + 1);
    }
    const char* bp = ldsb + cur * 13312;
    #pragma unroll
    for (int j = 0; j < 7; ++j) {
      if (j < nj) {
        half8 bh = *(const half8*)(bp + (jbase + j) * 1024 + lane * 16);
        #pragma unroll
        for (int f = 0; f < 4; ++f) {
          acc[f][j] = MFMAH(ah[f], bh, acc[f][j]);
          acc[f][j] = MFMAH(al_[f], bh, acc[f][j]);
        }
      }
    }
    __syncthreads();
    cur ^= 1;
    #pragma unroll
    for (int f = 0; f < 4; ++f) { ah[f] = nah[f]; al_[f] = nal[f]; }
  }

  float* red = (float*)ldsb;
  float q1[4][4], q2[4][4];
  #pragma unroll
  for (int f = 0; f < 4; ++f) {
    #pragma unroll
    for (int r = 0; r < 4; ++r) {
      float u = 0.f, vsq = 0.f;
      #pragma unroll
      for (int j = 0; j < 7; ++j) {
        float v = acc[f][j][r];
        u += v;
        vsq = fmaf(v, v, vsq);
      }
      #pragma unroll
      for (int off = 8; off; off >>= 1) {
        u += __shfl_xor(u, off, 16);
        vsq += __shfl_xor(vsq, off, 16);
      }
      q1[f][r] = u; q2[f][r] = vsq;
    }
  }
  int rowq = lane >> 4;
  bool wr = (lane & 15) == 0;
  if (wh == 0 && wr) {
    #pragma unroll
    for (int f = 0; f < 4; ++f)
      #pragma unroll
      for (int r = 0; r < 4; ++r) {
        int idx = wq * 64 + f * 16 + rowq * 4 + r;
        red[idx] = q1[f][r];
        red[128 + idx] = q2[f][r];
      }
  }
  __syncthreads();
  if (wh == 1 && wr) {
    size_t base = (size_t)nd * OC + ob * 128 + wq * 64;
    #pragma unroll
    for (int f = 0; f < 4; ++f)
      #pragma unroll
      for (int r = 0; r < 4; ++r) {
        int idx = f * 16 + rowq * 4 + r;
        S1[base + idx] = red[wq * 64 + idx] + q1[f][r];
        S2[base + idx] = red[128 + wq * 64 + idx] + q2[f][r];
      }
  }
}

// ---------------- head pass 1: dotW + IN + gelu + Wout partial (64-oc x 4-nd tiles) ----------------
__global__ __launch_bounds__(256) void head_gemm(
    const float* __restrict__ WvT, const float* __restrict__ sb,
    const float* __restrict__ S1, const float* __restrict__ S2,
    const float* __restrict__ gamma, const float* __restrict__ beta,
    const float* __restrict__ Wout, float* __restrict__ pb) {
  int bid = blockIdx.x;
  int ot = bid >> 4, nt = bid & 15;
  int o = ot >> 3, ct = ot & 7;
  int cb = ct * 64;
  int ndb = nt * 4;
  int t = threadIdx.x;
  int oc_l = t & 63, g = t >> 6;
  int nd = ndb + g;
  __shared__ float ssh[4][512];
  for (int i = t; i < 2048; i += 256) {
    int ir = i >> 9, ic = i & 511;
    ssh[ir][ic] = sb[((size_t)(ndb + ir) * 4 + o) * 512 + ic];
  }
  __syncthreads();
  const float* wcol = WvT + o * 512 + cb + oc_l;
  float acc = 0.f;
  #pragma unroll 8
  for (int cp = 0; cp < 512; ++cp) {
    float wv = wcol[(size_t)cp * 2048];
    acc = fmaf(wv, ssh[g][cp], acc);
  }
  int oc = o * 512 + cb + oc_l;
  float m1 = S1[(size_t)nd * OC + oc] * INV196;
  float m2 = S2[(size_t)nd * OC + oc] * INV196;
  float var = m2 - m1 * m1;
  float rs = rsqrtf(var + 1e-5f);
  float xh = (acc - m1) * rs * gamma[oc] + beta[oc];
  float ge = 0.5f * xh * (1.0f + erff(xh * 0.70710678118654752f));
  float p = ge * Wout[oc];
  #pragma unroll
  for (int off = 32; off; off >>= 1) p += __shfl_down(p, off, 64);
  if (oc_l == 0) pb[(ct * 4 + o) * 64 + nd] = p;
}

// ---------------- head pass 2: combine 8 c-tile partials + bias ----------------
__global__ void final_out(const float* __restrict__ pb, const float* __restrict__ bout,
                          float* __restrict__ outs) {
  int t = threadIdx.x;      // 256 = o(4) x nd(64)
  int o = t >> 6, nd = t & 63;
  float s = 0.f;
  #pragma unroll
  for (int ct = 0; ct < 8; ++ct) s += pb[(ct * 4 + o) * 64 + nd];
  outs[o * 64 + nd] = s + bout[o];
}

}  // namespace

extern "C" void kernel_launch(void* const* d_in, const int* in_sizes, int n_in,
                              void* d_out, int out_size, void* d_ws, size_t ws_size,
                              hipStream_t stream) {
  const float* x     = (const float*)d_in[0];
  const float* Wq    = (const float*)d_in[1];
  const float* Wk    = (const float*)d_in[2];
  const float* Wv    = (const float*)d_in[3];
  const float* gamma = (const float*)d_in[4];
  const float* beta  = (const float*)d_in[5];
  const float* Wout  = (const float*)d_in[6];
  const float* bout  = (const float*)d_in[7];
  float* out      = (float*)d_out;
  float* attn_out = out;            // (N,4,D,196) = 50176 floats
  float* outs     = out + 50176;    // (4,N,1,D)   = 256 floats

  float* ws = (float*)d_ws;
  float*     WvT = ws;                                  // [0, 1048576)
  _Float16*  WvA = (_Float16*)(ws + 1048576);           // 2097152 f16
  _Float16*  xpH = (_Float16*)(ws + 2097152);           // 7340032 f16
  _Float16*  xpL = (_Float16*)(ws + 5767168);           // 7340032 f16
  float*     xm  = ws + 9437184;                        // 32768
  float*     S1  = ws + 9469952;                        // 131072
  float*     S2  = ws + 9601024;                        // 131072
  float*     sb  = ws + 9732096;                        // 131072
  float*     pb  = ws + 9863168;                        // 2048

  fat_prep<<<4608, 256, 0, stream>>>(x, Wv, WvA, WvT, xpH, xpL, xm);
  fat_main<<<1280, 256, 0, stream>>>(WvA, xpH, xpL, Wq, Wk, xm,
                                     attn_out, sb, S1, S2);
  head_gemm<<<512, 256, 0, stream>>>(WvT, sb, S1, S2, gamma, beta, Wout, pb);
  final_out<<<1, 256, 0, stream>>>(pb, bout, outs);
}

// Round 9
// 122.387 us; speedup vs baseline: 3.1704x; 3.1704x over previous
//
#include <hip/hip_runtime.h>
#include <math.h>

namespace {

constexpr int Cc  = 512;
constexpr int HW  = 196;
constexpr int HWP = 224;
constexpr int OC  = 2048;
constexpr float TEMP   = 0.35355339059327373f;  // 1/sqrt(KEY_DIM)
constexpr float INV196 = 1.0f / 196.0f;

typedef __attribute__((ext_vector_type(8))) _Float16 half8;
typedef __attribute__((ext_vector_type(4))) float f32x4;

__device__ __forceinline__ void gload_lds16(const void* g, void* l) {
  __builtin_amdgcn_global_load_lds(
      (const __attribute__((address_space(1))) void*)g,
      (__attribute__((address_space(3))) void*)l, 16, 0, 0);
}

#define MFMAH(a, b, c) __builtin_amdgcn_mfma_f32_16x16x32_f16((a), (b), (c), 0, 0, 0)

// ================= K1: wv_prep (512 blocks) || pool (4096 blocks, XCD-affine) =================
__global__ __launch_bounds__(256) void fat_prep(
    const float* __restrict__ x, const float* __restrict__ Wv,
    _Float16* __restrict__ WvA, float* __restrict__ WvT,
    _Float16* __restrict__ xpH, _Float16* __restrict__ xpL,
    float* __restrict__ xm) {
  __shared__ char sm1[8448];
  int bid = blockIdx.x;
  int t = threadIdx.x;
  if (bid < 512) {
    // ---- wv_prep: WvA fragments + WvT transpose ----
    float* tile = (float*)sm1;          // [64][33]
    int kk = bid >> 5;
    int rq = bid & 31;
    int w = t >> 6, lane = t & 63;
    int r = rq * 4 + w;
    int oc = r * 16 + (lane & 15);
    int c0 = kk * 32 + (lane >> 4) * 8;
    const float* src = Wv + (size_t)oc * 512 + c0;
    float4 v0 = *(const float4*)src;
    float4 v1 = *(const float4*)(src + 4);
    float vals[8] = {v0.x, v0.y, v0.z, v0.w, v1.x, v1.y, v1.z, v1.w};
    half8 hi, lo;
    #pragma unroll
    for (int e = 0; e < 8; ++e) {
      _Float16 h = (_Float16)vals[e];
      hi[e] = h;
      lo[e] = (_Float16)(vals[e] - (float)h);
    }
    *(half8*)(WvA + ((size_t)(kk * 2 + 0) * 128 + r) * 512 + lane * 8) = hi;
    *(half8*)(WvA + ((size_t)(kk * 2 + 1) * 128 + r) * 512 + lane * 8) = lo;
    int ocl = w * 16 + (lane & 15);
    int cl = (lane >> 4) * 8;
    #pragma unroll
    for (int e = 0; e < 8; ++e) tile[ocl * 33 + cl + e] = vals[e];
    __syncthreads();
    int ocb = rq * 64;
    #pragma unroll
    for (int k2 = 0; k2 < 8; ++k2) {
      int idx = k2 * 256 + t;
      int c_l = idx >> 6, oc_l = idx & 63;
      WvT[(size_t)(kk * 32 + c_l) * 2048 + ocb + oc_l] = tile[oc_l * 33 + c_l];
    }
  } else {
    // ---- pool: avgpool3x3 + spatial mean -> f16 hi/lo xp [nd][hw][c] ----
    float* tl = (float*)sm1;            // [8][264]
    int pb = bid - 512;
    int nd = (((pb >> 9) & 7) << 3) | (pb & 7);   // XCD-affine
    int cg = (pb >> 3) & 63;
    int n = nd >> 5, d = nd & 31;
    int c0 = cg * 8;
    int cl = t >> 5, s = t & 31;
    const float* xr = x + (((size_t)(n * 512 + c0 + cl)) * 32 + d) * 256;
    float4 va = *(const float4*)(xr + s * 8);
    float4 vb = *(const float4*)(xr + s * 8 + 4);
    *(float4*)&tl[cl * 264 + s * 8] = va;
    *(float4*)&tl[cl * 264 + s * 8 + 4] = vb;
    float rs = va.x + va.y + va.z + va.w + vb.x + vb.y + vb.z + vb.w;
    #pragma unroll
    for (int off = 16; off; off >>= 1) rs += __shfl_xor(rs, off, 32);
    if (s == 0) xm[nd * 512 + c0 + cl] = rs * (1.0f / 256.0f);
    __syncthreads();
    if (t < HWP) {
      int hw = t;
      half8 hi, lo;
      if (hw < HW) {
        int y = hw / 14, xx = hw - y * 14;
        #pragma unroll
        for (int c = 0; c < 8; ++c) {
          const float* q = &tl[c * 264 + y * 16 + xx];
          float val = (q[0] + q[1] + q[2] + q[16] + q[17] + q[18] +
                       q[32] + q[33] + q[34]) * (1.0f / 9.0f);
          _Float16 h = (_Float16)val;
          hi[c] = h;
          lo[c] = (_Float16)(val - (float)h);
        }
      } else {
        #pragma unroll
        for (int c = 0; c < 8; ++c) { hi[c] = (_Float16)0.f; lo[c] = (_Float16)0.f; }
      }
      size_t off = ((size_t)nd * HWP + hw) * 512 + c0;
      *(half8*)(xpH + off) = hi;
      *(half8*)(xpL + off) = lo;
    }
  }
}

// ================= K2: attn (blocks 0..255, scheduled first) || moments (256..1279) ==========
// launch_bounds (256, 2): VGPR cap 128 — moments path needs ~104-112; (256,4)'s 64-cap
// spilled the acc[4][7] array to scratch (r8: 958 MB WRITE_SIZE, 6x slowdown).
__global__ __launch_bounds__(256, 2) void fat_main(
    const _Float16* __restrict__ WvA, const _Float16* __restrict__ xpH,
    const _Float16* __restrict__ xpL,
    const float* __restrict__ Wq, const float* __restrict__ Wk,
    const float* __restrict__ xm,
    float* __restrict__ attn_out, float* __restrict__ sb,
    float* __restrict__ S1, float* __restrict__ S2) {
  __shared__ char smem[26624];
  int bid = blockIdx.x;
  int t = threadIdx.x;
  int w = t >> 6, lane = t & 63;

  if (bid < 256) {
    // ---------------- attention path: q -> qw -> dots -> softmax -> s ----------------
    float* sred = (float*)smem;           // [4][512]
    float* xs   = (float*)(smem + 8192);  // [512]
    float* qw   = (float*)(smem + 10240); // [512]
    float* al   = (float*)(smem + 12288); // [196]
    float* qs   = (float*)(smem + 13072); // [8]
    float* redm = (float*)(smem + 13104); // [4]
    float* reds = (float*)(smem + 13120); // [4]
    int nd = ((bid >> 5) << 3) | (bid & 7);
    int o = (bid >> 3) & 3;
    int n = nd >> 5, d = nd & 31;
    xs[t] = xm[nd * 512 + t];
    xs[t + 256] = xm[nd * 512 + t + 256];
    __syncthreads();
    {
      int kd = t >> 5, j = t & 31;
      const float* wr = Wq + (size_t)(o * 8 + kd) * 512 + j * 16;
      const float* xr = xs + j * 16;
      float p = 0.f;
      #pragma unroll
      for (int i = 0; i < 16; ++i) p = fmaf(wr[i], xr[i], p);
      #pragma unroll
      for (int off = 16; off; off >>= 1) p += __shfl_xor(p, off, 32);
      if (j == 0) qs[kd] = p;
    }
    __syncthreads();
    #pragma unroll
    for (int i = 0; i < 2; ++i) {
      int c = t + i * 256;
      float a = 0.f;
      #pragma unroll
      for (int kd = 0; kd < 8; ++kd)
        a = fmaf(qs[kd], Wk[(size_t)(o * 8 + kd) * 512 + c], a);
      qw[c] = a;
    }
    __syncthreads();
    float dval = -3.0e38f;
    if (t < HW) {
      const half8* rh = (const half8*)(xpH + ((size_t)nd * HWP + t) * 512);
      const half8* rl = (const half8*)(xpL + ((size_t)nd * HWP + t) * 512);
      float acc = 0.f;
      for (int cb = 0; cb < 64; ++cb) {
        half8 h = rh[cb], l = rl[cb];
        #pragma unroll
        for (int e = 0; e < 8; ++e)
          acc = fmaf(qw[cb * 8 + e], (float)h[e] + (float)l[e], acc);
      }
      dval = acc * TEMP;
    }
    float m = dval;
    #pragma unroll
    for (int off = 32; off; off >>= 1) m = fmaxf(m, __shfl_xor(m, off, 64));
    if (lane == 0) redm[w] = m;
    __syncthreads();
    float bm = fmaxf(fmaxf(redm[0], redm[1]), fmaxf(redm[2], redm[3]));
    float e = (t < HW) ? expf(dval - bm) : 0.f;
    float sum = e;
    #pragma unroll
    for (int off = 32; off; off >>= 1) sum += __shfl_xor(sum, off, 64);
    if (lane == 0) reds[w] = sum;
    __syncthreads();
    float bs = reds[0] + reds[1] + reds[2] + reds[3];
    if (t < HW) {
      float a = e / bs;
      attn_out[(((size_t)n * 4 + o) * 32 + d) * HW + t] = a;
      al[t] = a;
    }
    __syncthreads();
    {
      float sa[8] = {0.f, 0.f, 0.f, 0.f, 0.f, 0.f, 0.f, 0.f};
      const _Float16* ph = xpH + (size_t)nd * HWP * 512 + lane * 8;
      const _Float16* pl = xpL + (size_t)nd * HWP * 512 + lane * 8;
      for (int hw = w; hw < HW; hw += 4) {
        half8 h = *(const half8*)(ph + (size_t)hw * 512);
        half8 l = *(const half8*)(pl + (size_t)hw * 512);
        float att = al[hw];
        #pragma unroll
        for (int e2 = 0; e2 < 8; ++e2)
          sa[e2] = fmaf(att, (float)h[e2] + (float)l[e2], sa[e2]);
      }
      float4 v0 = {sa[0], sa[1], sa[2], sa[3]};
      float4 v1 = {sa[4], sa[5], sa[6], sa[7]};
      *(float4*)&sred[w * 512 + lane * 8] = v0;
      *(float4*)&sred[w * 512 + lane * 8 + 4] = v1;
    }
    __syncthreads();
    #pragma unroll
    for (int i = 0; i < 2; ++i) {
      int c = t + i * 256;
      sb[((size_t)nd * 4 + o) * 512 + c] =
          sred[c] + sred[512 + c] + sred[1024 + c] + sred[1536 + c];
    }
    return;
  }

  // ---------------- moments path (identical to r7 moments_mfma) ----------------
  int b2 = bid - 256;
  int ob = (b2 >> 3) & 15;
  int nd = ((b2 >> 7) << 3) | (b2 & 7);
  int wq = w >> 1, wh = w & 1;
  int rbase = ob * 8 + wq * 4;
  int jbase = wh * 7;
  int nj = 7 - wh;
  char* ldsb = smem;
  const _Float16* xph = xpH + (size_t)nd * HWP * 512;

  f32x4 acc[4][7];
  #pragma unroll
  for (int f = 0; f < 4; ++f)
    #pragma unroll
    for (int j = 0; j < 7; ++j) acc[f][j] = (f32x4){0.f, 0.f, 0.f, 0.f};

  auto stage = [&](char* buf, int kk) {
    #pragma unroll
    for (int i = 0; i < 4; ++i) {
      if (i < 3 || t < 64) {
        int G = i * 256 + t;
        int j = G >> 6;
        int g = G & 63;              // == lane
        int hwl = g & 15, bb = g >> 4;
        const _Float16* src = xph + (size_t)(j * 16 + hwl) * 512 + kk * 32 + bb * 8;
        gload_lds16((const void*)src, (void*)(buf + G * 16));
      }
    }
  };

  stage(ldsb, 0);
  half8 ah[4], al_[4], nah[4], nal[4];
  #pragma unroll
  for (int f = 0; f < 4; ++f) {
    ah[f]  = *(const half8*)(WvA + ((size_t)0 * 128 + rbase + f) * 512 + lane * 8);
    al_[f] = *(const half8*)(WvA + ((size_t)1 * 128 + rbase + f) * 512 + lane * 8);
  }
  __syncthreads();

  int cur = 0;
  for (int kk = 0; kk < 16; ++kk) {
    if (kk < 15) {
      #pragma unroll
      for (int f = 0; f < 4; ++f) {
        nah[f] = *(const half8*)(WvA + ((size_t)((kk + 1) * 2 + 0) * 128 + rbase + f) * 512 + lane * 8);
        nal[f] = *(const half8*)(WvA + ((size_t)((kk + 1) * 2 + 1) * 128 + rbase + f) * 512 + lane * 8);
      }
      stage(ldsb + (cur ^ 1) * 13312, kk + 1);
    }
    const char* bp = ldsb + cur * 13312;
    #pragma unroll
    for (int j = 0; j < 7; ++j) {
      if (j < nj) {
        half8 bh = *(const half8*)(bp + (jbase + j) * 1024 + lane * 16);
        #pragma unroll
        for (int f = 0; f < 4; ++f) {
          acc[f][j] = MFMAH(ah[f], bh, acc[f][j]);
          acc[f][j] = MFMAH(al_[f], bh, acc[f][j]);
        }
      }
    }
    __syncthreads();
    cur ^= 1;
    #pragma unroll
    for (int f = 0; f < 4; ++f) { ah[f] = nah[f]; al_[f] = nal[f]; }
  }

  float* red = (float*)ldsb;
  float q1[4][4], q2[4][4];
  #pragma unroll
  for (int f = 0; f < 4; ++f) {
    #pragma unroll
    for (int r = 0; r < 4; ++r) {
      float u = 0.f, vsq = 0.f;
      #pragma unroll
      for (int j = 0; j < 7; ++j) {
        float v = acc[f][j][r];
        u += v;
        vsq = fmaf(v, v, vsq);
      }
      #pragma unroll
      for (int off = 8; off; off >>= 1) {
        u += __shfl_xor(u, off, 16);
        vsq += __shfl_xor(vsq, off, 16);
      }
      q1[f][r] = u; q2[f][r] = vsq;
    }
  }
  int rowq = lane >> 4;
  bool wr = (lane & 15) == 0;
  if (wh == 0 && wr) {
    #pragma unroll
    for (int f = 0; f < 4; ++f)
      #pragma unroll
      for (int r = 0; r < 4; ++r) {
        int idx = wq * 64 + f * 16 + rowq * 4 + r;
        red[idx] = q1[f][r];
        red[128 + idx] = q2[f][r];
      }
  }
  __syncthreads();
  if (wh == 1 && wr) {
    size_t base = (size_t)nd * OC + ob * 128 + wq * 64;
    #pragma unroll
    for (int f = 0; f < 4; ++f)
      #pragma unroll
      for (int r = 0; r < 4; ++r) {
        int idx = f * 16 + rowq * 4 + r;
        S1[base + idx] = red[wq * 64 + idx] + q1[f][r];
        S2[base + idx] = red[128 + wq * 64 + idx] + q2[f][r];
      }
  }
}

// ---------------- head pass 1: dotW + IN + gelu + Wout partial (64-oc x 4-nd tiles) ----------------
__global__ __launch_bounds__(256) void head_gemm(
    const float* __restrict__ WvT, const float* __restrict__ sb,
    const float* __restrict__ S1, const float* __restrict__ S2,
    const float* __restrict__ gamma, const float* __restrict__ beta,
    const float* __restrict__ Wout, float* __restrict__ pb) {
  int bid = blockIdx.x;
  int ot = bid >> 4, nt = bid & 15;
  int o = ot >> 3, ct = ot & 7;
  int cb = ct * 64;
  int ndb = nt * 4;
  int t = threadIdx.x;
  int oc_l = t & 63, g = t >> 6;
  int nd = ndb + g;
  __shared__ float ssh[4][512];
  for (int i = t; i < 2048; i += 256) {
    int ir = i >> 9, ic = i & 511;
    ssh[ir][ic] = sb[((size_t)(ndb + ir) * 4 + o) * 512 + ic];
  }
  __syncthreads();
  const float* wcol = WvT + o * 512 + cb + oc_l;
  float acc = 0.f;
  #pragma unroll 8
  for (int cp = 0; cp < 512; ++cp) {
    float wv = wcol[(size_t)cp * 2048];
    acc = fmaf(wv, ssh[g][cp], acc);
  }
  int oc = o * 512 + cb + oc_l;
  float m1 = S1[(size_t)nd * OC + oc] * INV196;
  float m2 = S2[(size_t)nd * OC + oc] * INV196;
  float var = m2 - m1 * m1;
  float rs = rsqrtf(var + 1e-5f);
  float xh = (acc - m1) * rs * gamma[oc] + beta[oc];
  float ge = 0.5f * xh * (1.0f + erff(xh * 0.70710678118654752f));
  float p = ge * Wout[oc];
  #pragma unroll
  for (int off = 32; off; off >>= 1) p += __shfl_down(p, off, 64);
  if (oc_l == 0) pb[(ct * 4 + o) * 64 + nd] = p;
}

// ---------------- head pass 2: combine 8 c-tile partials + bias ----------------
__global__ void final_out(const float* __restrict__ pb, const float* __restrict__ bout,
                          float* __restrict__ outs) {
  int t = threadIdx.x;      // 256 = o(4) x nd(64)
  int o = t >> 6, nd = t & 63;
  float s = 0.f;
  #pragma unroll
  for (int ct = 0; ct < 8; ++ct) s += pb[(ct * 4 + o) * 64 + nd];
  outs[o * 64 + nd] = s + bout[o];
}

}  // namespace

extern "C" void kernel_launch(void* const* d_in, const int* in_sizes, int n_in,
                              void* d_out, int out_size, void* d_ws, size_t ws_size,
                              hipStream_t stream) {
  const float* x     = (const float*)d_in[0];
  const float* Wq    = (const float*)d_in[1];
  const float* Wk    = (const float*)d_in[2];
  const float* Wv    = (const float*)d_in[3];
  const float* gamma = (const float*)d_in[4];
  const float* beta  = (const float*)d_in[5];
  const float* Wout  = (const float*)d_in[6];
  const float* bout  = (const float*)d_in[7];
  float* out      = (float*)d_out;
  float* attn_out = out;            // (N,4,D,196) = 50176 floats
  float* outs     = out + 50176;    // (4,N,1,D)   = 256 floats

  float* ws = (float*)d_ws;
  float*     WvT = ws;                                  // [0, 1048576)
  _Float16*  WvA = (_Float16*)(ws + 1048576);           // 2097152 f16
  _Float16*  xpH = (_Float16*)(ws + 2097152);           // 7340032 f16
  _Float16*  xpL = (_Float16*)(ws + 5767168);           // 7340032 f16
  float*     xm  = ws + 9437184;                        // 32768
  float*     S1  = ws + 9469952;                        // 131072
  float*     S2  = ws + 9601024;                        // 131072
  float*     sb  = ws + 9732096;                        // 131072
  float*     pb  = ws + 9863168;                        // 2048

  fat_prep<<<4608, 256, 0, stream>>>(x, Wv, WvA, WvT, xpH, xpL, xm);
  fat_main<<<1280, 256, 0, stream>>>(WvA, xpH, xpL, Wq, Wk, xm,
                                     attn_out, sb, S1, S2);
  head_gemm<<<512, 256, 0, stream>>>(WvT, sb, S1, S2, gamma, beta, Wout, pb);
  final_out<<<1, 256, 0, stream>>>(pb, bout, outs);
}